// Round 9
// baseline (406.983 us; speedup 1.0000x reference)
//
#include <hip/hip_runtime.h>

typedef __attribute__((ext_vector_type(8))) short bf16x8;
typedef __attribute__((ext_vector_type(4))) float f32x4;

#define MFMA16(a, b, c) __builtin_amdgcn_mfma_f32_16x16x32_bf16((a), (b), (c), 0, 0, 0)

static __device__ __forceinline__ short f2bf(float f) {
  unsigned u = __builtin_bit_cast(unsigned, f);
  unsigned r = (u + 0x7FFFu + ((u >> 16) & 1u)) >> 16;
  return (short)(unsigned short)r;
}
static __device__ __forceinline__ unsigned pack2(float lo, float hi) {
  return (unsigned)(unsigned short)f2bf(lo) | ((unsigned)(unsigned short)f2bf(hi) << 16);
}

// async global->LDS, 16B per lane
static __device__ __forceinline__ void glds16(const void* g, void* l) {
  __builtin_amdgcn_global_load_lds((const __attribute__((address_space(1))) unsigned*)g,
                                   (__attribute__((address_space(3))) unsigned*)l, 16, 0, 0);
}

// ---------------- fused prep: x->bf16 cvt + both weight transposes ----------------
__global__ __launch_bounds__(256) void prep_kernel(const float* __restrict__ x,
                                                   short* __restrict__ x_bf,
                                                   const float* __restrict__ W_attn,
                                                   short* __restrict__ wt_attn,
                                                   const float* __restrict__ W_proj,
                                                   short* __restrict__ wt_proj) {
  __shared__ float tile[64][65];
  int bid = blockIdx.x;
  if (bid < 4096) {
    size_t i = ((size_t)bid * 256 + threadIdx.x) * 8;
    float4 a = *(const float4*)(x + i);
    float4 b = *(const float4*)(x + i + 4);
    uint4 o;
    o.x = pack2(a.x, a.y);
    o.y = pack2(a.z, a.w);
    o.z = pack2(b.x, b.y);
    o.w = pack2(b.z, b.w);
    *(uint4*)(x_bf + i) = o;
    return;
  }
  const float* in;
  short* out;
  int R = 2048, Cc, r0, c0;
  if (bid < 7168) {
    int r = bid - 4096;  // 96 x 32
    in = W_attn; out = wt_attn; Cc = 6144;
    c0 = (r % 96) * 64; r0 = (r / 96) * 64;
  } else {
    int r = bid - 7168;  // 32 x 32
    in = W_proj; out = wt_proj; Cc = 2048;
    c0 = (r & 31) * 64; r0 = (r >> 5) * 64;
  }
  int tx = threadIdx.x & 15, ty = threadIdx.x >> 4;
#pragma unroll
  for (int i = 0; i < 4; i++) {
    int r = ty + i * 16;
    float4 v = *(const float4*)(in + (size_t)(r0 + r) * Cc + c0 + tx * 4);
    tile[r][tx * 4 + 0] = v.x;
    tile[r][tx * 4 + 1] = v.y;
    tile[r][tx * 4 + 2] = v.z;
    tile[r][tx * 4 + 3] = v.w;
  }
  __syncthreads();
#pragma unroll
  for (int i = 0; i < 4; i++) {
    int co = ty + i * 16;
    uint2 o;
    o.x = pack2(tile[tx * 4 + 0][co], tile[tx * 4 + 1][co]);
    o.y = pack2(tile[tx * 4 + 2][co], tile[tx * 4 + 3][co]);
    *(uint2*)(out + (size_t)(c0 + co) * R + r0 + tx * 4) = o;
  }
}

// ============ 256x128 GEMM core, BK=64 single-phase, 3-buffer rotation ============
// BM=256, BN=128, BK=64, 8 waves (4M x 2N), wave tile 64x64 (acc[4][4]).
// LDS 144 KiB: 3 buffers x (A 32KB + B 16KB). Buffer layout: A[2 ks][16 grp][1KB
// swizzled subtile] then B[2 ks][8 grp][1KB]. st_16x32 swizzle unchanged (per-subtile):
// pre-swizzled global source + swizzled ds_read offset.
// Phase t (t=0..31): read buf t%3 (= K-tile t, staged at t-2), 16 ds_read_b128 ->
// 32 MFMA (one barrier-pair per 64-K vs two before: half the syncs, 2x MFMA cluster);
// stage K-tile t+2 into buf (t+2)%3 (overwrites the buffer read at t-1 -- all waves'
// reads of it completed before t-1's end barrier). vmcnt(6) every phase end
// (guarantees the 2-phase-old 6 loads landed). Prologue: KT0,KT1 + vmcnt(6).
// Tail t=30,31: dummy re-stage KT31 into dead buffers; vmcnt(0) before epilogue.

#define AFQ3(C, KS, MT) \
  (*(const bf16x8*)&lds[(C)*24576 + (KS)*8192 + (wr4 + (MT)) * 512 + rdoff])
#define BFQ3(C, KS, NT) \
  (*(const bf16x8*)&lds[(C)*24576 + 16384 + (KS)*4096 + (wc4 + (NT)) * 512 + rdoff])

#define STAGE3(C, KT)                                                     \
  do {                                                                    \
    glds16(Asrc0 + (KT) * 64, &lds[(C)*24576 + wid * 512]);               \
    glds16(Asrc1 + (KT) * 64, &lds[(C)*24576 + (wid + 8) * 512]);         \
    glds16(Asrc0 + (KT) * 64 + 32, &lds[(C)*24576 + 8192 + wid * 512]);   \
    glds16(Asrc1 + (KT) * 64 + 32,                                        \
           &lds[(C)*24576 + 8192 + (wid + 8) * 512]);                     \
    glds16(Bsrc0 + (KT) * 64, &lds[(C)*24576 + 16384 + wid * 512]);       \
    glds16(Bsrc0 + (KT) * 64 + 32, &lds[(C)*24576 + 20480 + wid * 512]);  \
  } while (0)

#define MIDBAR                                                       \
  do {                                                               \
    asm volatile("s_barrier\n\ts_waitcnt lgkmcnt(0)" ::: "memory");  \
    __builtin_amdgcn_sched_barrier(0);                               \
  } while (0)
#define ENDBARV6                                                     \
  do {                                                               \
    __builtin_amdgcn_sched_barrier(0);                               \
    asm volatile("s_waitcnt vmcnt(6)\n\ts_barrier" ::: "memory");    \
    __builtin_amdgcn_sched_barrier(0);                               \
  } while (0)

#define MMROW(AR, BV, MT)                            \
  do {                                               \
    acc[MT][0] = MFMA16(AR, BV[0], acc[MT][0]);      \
    acc[MT][1] = MFMA16(AR, BV[1], acc[MT][1]);      \
    acc[MT][2] = MFMA16(AR, BV[2], acc[MT][2]);      \
    acc[MT][3] = MFMA16(AR, BV[3], acc[MT][3]);      \
  } while (0)

#define PHASE64(C, CN, KT)         \
  do {                             \
    af[0] = AFQ3(C, 0, 0);         \
    af[1] = AFQ3(C, 0, 1);         \
    af[2] = AFQ3(C, 0, 2);         \
    af[3] = AFQ3(C, 0, 3);         \
    bfr[0] = BFQ3(C, 0, 0);        \
    bfr[1] = BFQ3(C, 0, 1);        \
    bfr[2] = BFQ3(C, 0, 2);        \
    bfr[3] = BFQ3(C, 0, 3);        \
    ag[0] = AFQ3(C, 1, 0);         \
    ag[1] = AFQ3(C, 1, 1);         \
    ag[2] = AFQ3(C, 1, 2);         \
    ag[3] = AFQ3(C, 1, 3);         \
    bg[0] = BFQ3(C, 1, 0);         \
    bg[1] = BFQ3(C, 1, 1);         \
    bg[2] = BFQ3(C, 1, 2);         \
    bg[3] = BFQ3(C, 1, 3);         \
    STAGE3(CN, KT);                \
    MIDBAR;                        \
    __builtin_amdgcn_s_setprio(1); \
    MMROW(af[0], bfr, 0);          \
    MMROW(af[1], bfr, 1);          \
    MMROW(af[2], bfr, 2);          \
    MMROW(af[3], bfr, 3);          \
    MMROW(ag[0], bg, 0);           \
    MMROW(ag[1], bg, 1);           \
    MMROW(ag[2], bg, 2);           \
    MMROW(ag[3], bg, 3);           \
    __builtin_amdgcn_s_setprio(0); \
    ENDBARV6;                      \
  } while (0)

#define GEMM_PREAMBLE(Aptr, Bptr)                                                  \
  __shared__ __align__(16) short lds[73728]; /* 144 KiB */                         \
  int tid = threadIdx.x;                                                           \
  int lane = tid & 63, wid = tid >> 6;                                             \
  int l15 = lane & 15, l4 = lane >> 4;                                             \
  int wr = wid >> 1, wc = wid & 1;                                                 \
  int wr4 = wr * 4, wc4 = wc * 4;                                                  \
  int wprime = (lane * 16) ^ (lane & 32);                                          \
  int r_ = wprime >> 6;                                                            \
  int cs_ = (wprime & 63) >> 1;                                                    \
  const short* Asrc0 = (Aptr) + (size_t)(rowBase + wid * 16 + r_) * 2048 + cs_;    \
  const short* Asrc1 = (Aptr) + (size_t)(rowBase + (wid + 8) * 16 + r_) * 2048 + cs_; \
  const short* Bsrc0 = (Bptr) + (size_t)(colBase + wid * 16 + r_) * 2048 + cs_;    \
  int rdoff = l15 * 32 + ((l4 * 8) ^ ((l15 & 8) << 1));                            \
  f32x4 zero = {0.f, 0.f, 0.f, 0.f};                                               \
  f32x4 acc[4][4];                                                                 \
  _Pragma("unroll") for (int i = 0; i < 4; i++) _Pragma("unroll") for (int j = 0;  \
                                                                       j < 4; j++) \
      acc[i][j] = zero;                                                            \
  bf16x8 af[4], bfr[4], ag[4], bg[4];                                              \
  STAGE3(0, 0);                                                                    \
  STAGE3(1, 1);                                                                    \
  asm volatile("s_waitcnt vmcnt(6)" ::: "memory");                                 \
  __builtin_amdgcn_sched_barrier(0);                                               \
  asm volatile("s_barrier" ::: "memory");                                          \
  __builtin_amdgcn_sched_barrier(0);                                               \
  for (int t = 0; t < 30; t += 3) {                                                \
    PHASE64(0, 2, t + 2);                                                          \
    PHASE64(1, 0, t + 3);                                                          \
    PHASE64(2, 1, t + 4);                                                          \
  }                                                                                \
  PHASE64(0, 2, 31); /* t=30: reads KT30; dummy re-stage into dead buf */          \
  PHASE64(1, 0, 31); /* t=31: reads KT31; dummy */                                 \
  asm volatile("s_waitcnt vmcnt(0)" ::: "memory");                                 \
  __syncthreads();

// ---------------- QKV GEMM: grid 768 (= 3 exact rounds), R3 swizzle ----------------
__global__ __launch_bounds__(512, 2) void gemm_qkv_kernel(const short* __restrict__ A,
                                                          const short* __restrict__ Bt,
                                                          const float* __restrict__ bias,
                                                          short* __restrict__ q_bf,
                                                          short* __restrict__ k_bf,
                                                          short* __restrict__ vt,
                                                          float* __restrict__ cache) {
  int bid = blockIdx.x;  // R3 XCD-aware swizzle
  int s = (bid & 7) * 96 + (bid >> 3);
  int bx = s % 48, by = s / 48;
  int rowBase = by * 256, colBase = bx * 128;

  GEMM_PREAMBLE(A, Bt)

  // ---- epilogue ----
  int seg = colBase >> 11;      // 0=q 1=k 2=v (block-uniform: 16 blocks/segment)
  int colLoc = colBase & 2047;  // column within segment
  float scale = (seg == 0) ? 0.08838834764831845f : 1.0f;
  float bv[4];
#pragma unroll
  for (int nt = 0; nt < 4; nt++) bv[nt] = bias[colBase + wc * 64 + nt * 16 + l15];

  // stage C tile (256x128 bf16) through LDS
  short(*Cs)[136] = (short(*)[136])lds;  // 256 x 136 shorts = 68 KiB < 144 KiB
#pragma unroll
  for (int mt = 0; mt < 4; mt++)
#pragma unroll
    for (int nt = 0; nt < 4; nt++)
#pragma unroll
      for (int r = 0; r < 4; r++)
        Cs[wr * 64 + mt * 16 + l4 * 4 + r][wc * 64 + nt * 16 + l15] =
            f2bf((acc[mt][nt][r] + bv[nt]) * scale);
  __syncthreads();

  if (seg < 2) {  // q/k: linear 256B-contiguous stores
    short* outp = (seg == 0) ? q_bf : k_bf;
#pragma unroll
    for (int pp = 0; pp < 8; pp++) {
      int idx = pp * 512 + tid;
      int row = idx >> 4, c8 = (idx & 15) * 8;
      *(uint4*)(outp + (size_t)(rowBase + row) * 2048 + colLoc + c8) =
          *(const uint4*)&Cs[row][c8];
    }
  } else {  // v: permuted transpose to vt (fused vpost)
    int b_ = rowBase >> 11, rowLoc = rowBase & 2047;
    int hh = colLoc >> 7;  // this block's head
    short* vrow = vt + (size_t)((b_ * 16 + hh) * 128) * 2048;
    int tx = tid & 7, dbase = tid >> 3;  // dbase in 0..63
#pragma unroll
    for (int dd = 0; dd < 2; dd++) {
      int d = dbase + dd * 64;
#pragma unroll
      for (int g = 0; g < 4; g++) {
        short tmp[8];
#pragma unroll
        for (int j = 0; j < 8; j++) {
          int p = tx * 8 + j;
          int tl = (p & 32) + ((p & 1) << 4) + ((p >> 1) & 15);
          tmp[j] = Cs[g * 64 + tl][d];
        }
        *(uint4*)(vrow + (size_t)d * 2048 + rowLoc + g * 64 + tx * 8) = *(uint4*)tmp;
      }
    }
  }

  if (seg) {  // fp32 cache: k -> +0, v -> +2048 ; row index == b*2048+t
    int coff = (seg == 1) ? 0 : 2048;
#pragma unroll
    for (int mt = 0; mt < 4; mt++)
#pragma unroll
      for (int nt = 0; nt < 4; nt++) {
        int cc = coff + colLoc + wc * 64 + nt * 16 + l15;
#pragma unroll
        for (int r = 0; r < 4; r++) {
          int row = rowBase + wr * 64 + mt * 16 + l4 * 4 + r;
          cache[(size_t)row * 4096 + cc] = acc[mt][nt][r] + bv[nt];
        }
      }
  }
}

// ---------------- proj GEMM: same core, grid 256, R3 swizzle ----------------
__global__ __launch_bounds__(512, 2) void gemm_proj_kernel(const short* __restrict__ A,
                                                           const short* __restrict__ Bt,
                                                           const float* __restrict__ bias,
                                                           float* __restrict__ out_y) {
  int bid = blockIdx.x;  // R3 mapping
  int s = (bid & 7) * 32 + (bid >> 3);
  int bx = s % 16, by = s / 16;
  int rowBase = by * 256, colBase = bx * 128;

  GEMM_PREAMBLE(A, Bt)

#pragma unroll
  for (int mt = 0; mt < 4; mt++)
#pragma unroll
    for (int nt = 0; nt < 4; nt++) {
      int col = colBase + wc * 64 + nt * 16 + l15;
      float bvv = bias[col];
#pragma unroll
      for (int r = 0; r < 4; r++) {
        int row = rowBase + wr * 64 + mt * 16 + l4 * 4 + r;
        out_y[(size_t)row * 2048 + col] = acc[mt][nt][r] + bvv;  // 64B runs
      }
    }
}

// ---------------- fused causal flash attention (R4/R7 proven 8-wave version) ----------------
#define LDK 136  // K rows: 128 + 8 pad shorts
#define LDV 72   // V rows: 64 + 8 pad
#define LDP 72   // P rows: 64 + 8 pad

__global__ __launch_bounds__(512, 2) void attn_kernel(const short* __restrict__ qb,
                                                      const short* __restrict__ kb,
                                                      const short* __restrict__ vtb,
                                                      short* __restrict__ attout) {
  __shared__ short Ks[64 * LDK];      // 64 k x 128 d
  __shared__ short Vs[128 * LDV];     // 128 d x 64 k (t-permuted)
  __shared__ short Ps[8][32 * LDP];   // per wave: 32 q-rows x 64 k (t-permuted)

  int tid = threadIdx.x;
  int lane = tid & 63, wid = tid >> 6;
  int l15 = lane & 15, l4 = lane >> 4;
  int qlo = blockIdx.x, qhi = 15 - qlo;  // 128-row tile indices
  int h = blockIdx.y, b = blockIdx.z;
  int myqt = (wid < 4) ? qhi : qlo;
  int qrow0 = myqt * 128 + (wid & 3) * 32;  // this wave's 32 rows
  int kdiag = qrow0 >> 6;                   // the single diagonal k-tile for this wave
  int ktmax = 2 * qhi + 1;                  // block staging loop bound
  size_t qkbase = (size_t)b * 2048 * 2048 + (size_t)h * 128;
  size_t vbase = (size_t)((b * 16 + h) * 128) * 2048;

  bf16x8 qf[2][4];
#pragma unroll
  for (int m = 0; m < 2; m++)
#pragma unroll
    for (int kk = 0; kk < 4; kk++)
      qf[m][kk] =
          *(const bf16x8*)(qb + qkbase + (size_t)(qrow0 + m * 16 + l15) * 2048 + kk * 32 + l4 * 8);

  short onev = (short)0x3F80;  // bf16 1.0
  bf16x8 ones = {onev, onev, onev, onev, onev, onev, onev, onev};

  f32x4 zero = {0.f, 0.f, 0.f, 0.f};
  f32x4 o[2][8], ol[2];
#pragma unroll
  for (int m = 0; m < 2; m++) {
#pragma unroll
    for (int n = 0; n < 8; n++) o[m][n] = zero;
    ol[m] = zero;
  }

  // staging geometry (512 threads cover K 64x128 and V 128x64, 2 uint4 each)
  int c0 = tid, c1 = 512 + tid;
  int kr0 = c0 >> 4, kc0 = (c0 & 15) * 8;
  int kr1 = c1 >> 4, kc1 = (c1 & 15) * 8;
  int dr0 = c0 >> 3, tc0 = (c0 & 7) * 8;
  int dr1 = c1 >> 3, tc1 = (c1 & 7) * 8;
  const short* kA = kb + qkbase + (size_t)kr0 * 2048 + kc0;
  const short* kB = kb + qkbase + (size_t)kr1 * 2048 + kc1;
  const short* vA = vtb + vbase + (size_t)dr0 * 2048 + tc0;
  const short* vB = vtb + vbase + (size_t)dr1 * 2048 + tc1;

  // T14 prefetch: kt=0 tile -> regs
  uint4 krg0 = *(const uint4*)kA;
  uint4 krg1 = *(const uint4*)kB;
  uint4 vrg0 = *(const uint4*)vA;
  uint4 vrg1 = *(const uint4*)vB;

  for (int kt = 0; kt <= ktmax; kt++) {
    __syncthreads();  // previous tile's LDS reads complete
    *(uint4*)&Ks[kr0 * LDK + kc0] = krg0;
    *(uint4*)&Ks[kr1 * LDK + kc1] = krg1;
    *(uint4*)&Vs[dr0 * LDV + tc0] = vrg0;
    *(uint4*)&Vs[dr1 * LDV + tc1] = vrg1;
    if (kt < ktmax) {  // issue next-tile loads; latency hides under compute
      size_t ko = (size_t)(kt + 1) * 64 * 2048;
      int vo = (kt + 1) * 64;
      krg0 = *(const uint4*)(kA + ko);
      krg1 = *(const uint4*)(kB + ko);
      vrg0 = *(const uint4*)(vA + vo);
      vrg1 = *(const uint4*)(vB + vo);
    }
    __syncthreads();

    if (kt <= kdiag) {
      f32x4 s[2][4];
#pragma unroll
      for (int m = 0; m < 2; m++)
#pragma unroll
        for (int nt = 0; nt < 4; nt++) s[m][nt] = zero;
#pragma unroll
      for (int kk = 0; kk < 4; kk++) {
#pragma unroll
        for (int nt = 0; nt < 4; nt++) {
          bf16x8 kf = *(const bf16x8*)&Ks[(nt * 16 + l15) * LDK + kk * 32 + l4 * 8];
          s[0][nt] = MFMA16(qf[0][kk], kf, s[0][nt]);
          s[1][nt] = MFMA16(qf[1][kk], kf, s[1][nt]);
        }
      }

      if (kt == kdiag) {
        int kt0 = kt * 64;
#pragma unroll
        for (int m = 0; m < 2; m++)
#pragma unroll
          for (int nt = 0; nt < 4; nt++) {
            int colg = kt0 + nt * 16 + l15;
#pragma unroll
            for (int r = 0; r < 4; r++) {
              int rowg = qrow0 + m * 16 + l4 * 4 + r;
              if (colg > rowg) s[m][nt][r] = -1e30f;
            }
          }
      }

#pragma unroll
      for (int m = 0; m < 2; m++)
#pragma unroll
        for (int r = 0; r < 4; r++) {
          float p0 = __expf(s[m][0][r]);
          float p1 = __expf(s[m][1][r]);
          float p2 = __expf(s[m][2][r]);
          float p3 = __expf(s[m][3][r]);
          int prow = (m * 16 + l4 * 4 + r) * LDP;
          *(unsigned*)&Ps[wid][prow + 2 * l15] = pack2(p0, p1);
          *(unsigned*)&Ps[wid][prow + 32 + 2 * l15] = pack2(p2, p3);
        }

#pragma unroll
      for (int kk = 0; kk < 2; kk++) {
        bf16x8 pf0 = *(const bf16x8*)&Ps[wid][l15 * LDP + kk * 32 + l4 * 8];
        bf16x8 pf1 = *(const bf16x8*)&Ps[wid][(16 + l15) * LDP + kk * 32 + l4 * 8];
        ol[0] = MFMA16(pf0, ones, ol[0]);
        ol[1] = MFMA16(pf1, ones, ol[1]);
#pragma unroll
        for (int n = 0; n < 8; n++) {
          bf16x8 vf = *(const bf16x8*)&Vs[(n * 16 + l15) * LDV + kk * 32 + l4 * 8];
          o[0][n] = MFMA16(pf0, vf, o[0][n]);
          o[1][n] = MFMA16(pf1, vf, o[1][n]);
        }
      }
    }
  }

#pragma unroll
  for (int m = 0; m < 2; m++) {
    float rl[4];
#pragma unroll
    for (int r = 0; r < 4; r++) rl[r] = 1.0f / ol[m][r];
#pragma unroll
    for (int n = 0; n < 8; n++)
#pragma unroll
      for (int r = 0; r < 4; r++)
        attout[qkbase + (size_t)(qrow0 + m * 16 + l4 * 4 + r) * 2048 + n * 16 + l15] =
            f2bf(o[m][n][r] * rl[r]);
  }
}

// ---------------- launch ----------------
extern "C" void kernel_launch(void* const* d_in, const int* in_sizes, int n_in, void* d_out,
                              int out_size, void* d_ws, size_t ws_size, hipStream_t stream) {
  const float* x = (const float*)d_in[0];
  const float* W_attn = (const float*)d_in[2];
  const float* b_attn = (const float*)d_in[3];
  const float* W_proj = (const float*)d_in[4];
  const float* b_proj = (const float*)d_in[5];
  float* y = (float*)d_out;
  float* cache = y + (size_t)4096 * 2048;

  char* p = (char*)d_ws;
  short* x_bf = (short*)p;   p += (size_t)8388608 * 2;
  short* q_bf = (short*)p;   p += (size_t)8388608 * 2;
  short* k_bf = (short*)p;   p += (size_t)8388608 * 2;
  short* vt_bf = (short*)p;  p += (size_t)8388608 * 2;
  short* att_bf = (short*)p; p += (size_t)8388608 * 2;
  short* wt_attn = (short*)p; p += (size_t)12582912 * 2;
  short* wt_proj = (short*)p; p += (size_t)4194304 * 2;

  prep_kernel<<<8192, 256, 0, stream>>>(x, x_bf, W_attn, wt_attn, W_proj, wt_proj);
  gemm_qkv_kernel<<<768, 512, 0, stream>>>(x_bf, wt_attn, b_attn, q_bf, k_bf, vt_bf, cache);
  attn_kernel<<<dim3(8, 16, 2), 512, 0, stream>>>(q_bf, k_bf, vt_bf, att_bf);
  gemm_proj_kernel<<<256, 512, 0, stream>>>(att_bf, wt_proj, b_proj, y);
}

// Round 10
// 394.849 us; speedup vs baseline: 1.0307x; 1.0307x over previous
//
#include <hip/hip_runtime.h>

typedef __attribute__((ext_vector_type(8))) short bf16x8;
typedef __attribute__((ext_vector_type(4))) float f32x4;

#define MFMA16(a, b, c) __builtin_amdgcn_mfma_f32_16x16x32_bf16((a), (b), (c), 0, 0, 0)

static __device__ __forceinline__ short f2bf(float f) {
  unsigned u = __builtin_bit_cast(unsigned, f);
  unsigned r = (u + 0x7FFFu + ((u >> 16) & 1u)) >> 16;
  return (short)(unsigned short)r;
}
static __device__ __forceinline__ unsigned pack2(float lo, float hi) {
  return (unsigned)(unsigned short)f2bf(lo) | ((unsigned)(unsigned short)f2bf(hi) << 16);
}

// async global->LDS, 16B per lane
static __device__ __forceinline__ void glds16(const void* g, void* l) {
  __builtin_amdgcn_global_load_lds((const __attribute__((address_space(1))) unsigned*)g,
                                   (__attribute__((address_space(3))) unsigned*)l, 16, 0, 0);
}

// ---------------- fused prep: x->bf16 cvt + both weight transposes ----------------
__global__ __launch_bounds__(256) void prep_kernel(const float* __restrict__ x,
                                                   short* __restrict__ x_bf,
                                                   const float* __restrict__ W_attn,
                                                   short* __restrict__ wt_attn,
                                                   const float* __restrict__ W_proj,
                                                   short* __restrict__ wt_proj) {
  __shared__ float tile[64][65];
  int bid = blockIdx.x;
  if (bid < 4096) {
    size_t i = ((size_t)bid * 256 + threadIdx.x) * 8;
    float4 a = *(const float4*)(x + i);
    float4 b = *(const float4*)(x + i + 4);
    uint4 o;
    o.x = pack2(a.x, a.y);
    o.y = pack2(a.z, a.w);
    o.z = pack2(b.x, b.y);
    o.w = pack2(b.z, b.w);
    *(uint4*)(x_bf + i) = o;
    return;
  }
  const float* in;
  short* out;
  int R = 2048, Cc, r0, c0;
  if (bid < 7168) {
    int r = bid - 4096;  // 96 x 32
    in = W_attn; out = wt_attn; Cc = 6144;
    c0 = (r % 96) * 64; r0 = (r / 96) * 64;
  } else {
    int r = bid - 7168;  // 32 x 32
    in = W_proj; out = wt_proj; Cc = 2048;
    c0 = (r & 31) * 64; r0 = (r >> 5) * 64;
  }
  int tx = threadIdx.x & 15, ty = threadIdx.x >> 4;
#pragma unroll
  for (int i = 0; i < 4; i++) {
    int r = ty + i * 16;
    float4 v = *(const float4*)(in + (size_t)(r0 + r) * Cc + c0 + tx * 4);
    tile[r][tx * 4 + 0] = v.x;
    tile[r][tx * 4 + 1] = v.y;
    tile[r][tx * 4 + 2] = v.z;
    tile[r][tx * 4 + 3] = v.w;
  }
  __syncthreads();
#pragma unroll
  for (int i = 0; i < 4; i++) {
    int co = ty + i * 16;
    uint2 o;
    o.x = pack2(tile[tx * 4 + 0][co], tile[tx * 4 + 1][co]);
    o.y = pack2(tile[tx * 4 + 2][co], tile[tx * 4 + 3][co]);
    *(uint2*)(out + (size_t)(c0 + co) * R + r0 + tx * 4) = o;
  }
}

// ============ 256x128 8-phase-schedule GEMM core (T2+T4+T5) — R8 proven ============
// 2 phases per 64-K tile, each {8 ds_read, 3 glds, 2 barriers, 16 MFMA}; depth-3
// counted vmcnt(6); st_16x32 swizzle via pre-swizzled global source + swizzled
// ds_read. R9's BK=64 single-phase variant regressed (coarse phases lose the fine
// interleave, m196) — this granularity is the measured optimum for this tile shape.

#define AFQ(C, KS, MT) (*(const bf16x8*)&lds[(C)*16384 + (KS)*8192 + (wr4 + (MT)) * 512 + rdoff])
#define BFQ(C, KS, NT) \
  (*(const bf16x8*)&lds[32768 + (C)*8192 + (KS)*4096 + (wc4 + (NT)) * 512 + rdoff])

#define STAGE(C, KS, KT)                                                           \
  do {                                                                             \
    glds16(Asrc0 + (KT) * 64 + (KS) * 32, &lds[(C)*16384 + (KS)*8192 + wid * 512]); \
    glds16(Asrc1 + (KT) * 64 + (KS) * 32,                                          \
           &lds[(C)*16384 + (KS)*8192 + (wid + 8) * 512]);                         \
    glds16(Bsrc0 + (KT) * 64 + (KS) * 32,                                          \
           &lds[32768 + (C)*8192 + (KS)*4096 + wid * 512]);                        \
  } while (0)

#define MIDBAR                                                       \
  do {                                                               \
    asm volatile("s_barrier\n\ts_waitcnt lgkmcnt(0)" ::: "memory");  \
    __builtin_amdgcn_sched_barrier(0);                               \
  } while (0)
#define ENDBARV6                                                     \
  do {                                                               \
    __builtin_amdgcn_sched_barrier(0);                               \
    asm volatile("s_waitcnt vmcnt(6)\n\ts_barrier" ::: "memory");    \
    __builtin_amdgcn_sched_barrier(0);                               \
  } while (0)

#define MMROW(AR, MT)                            \
  do {                                           \
    acc[MT][0] = MFMA16(AR, bfr[0], acc[MT][0]); \
    acc[MT][1] = MFMA16(AR, bfr[1], acc[MT][1]); \
    acc[MT][2] = MFMA16(AR, bfr[2], acc[MT][2]); \
    acc[MT][3] = MFMA16(AR, bfr[3], acc[MT][3]); \
  } while (0)

#define PHASE(C, KS, STG)          \
  do {                             \
    af[0] = AFQ(C, KS, 0);         \
    af[1] = AFQ(C, KS, 1);         \
    af[2] = AFQ(C, KS, 2);         \
    af[3] = AFQ(C, KS, 3);         \
    bfr[0] = BFQ(C, KS, 0);        \
    bfr[1] = BFQ(C, KS, 1);        \
    bfr[2] = BFQ(C, KS, 2);        \
    bfr[3] = BFQ(C, KS, 3);        \
    STG;                           \
    MIDBAR;                        \
    __builtin_amdgcn_s_setprio(1); \
    MMROW(af[0], 0);               \
    MMROW(af[1], 1);               \
    MMROW(af[2], 2);               \
    MMROW(af[3], 3);               \
    __builtin_amdgcn_s_setprio(0); \
    ENDBARV6;                      \
  } while (0)

#define KTILE(C, NX, MM)                     \
  do {                                       \
    int s1 = (MM) + 1 > 31 ? 31 : (MM) + 1;  \
    int s2 = (MM) + 2 > 31 ? 31 : (MM) + 2;  \
    PHASE(C, 0, STAGE(NX, 1, s1));           \
    PHASE(C, 1, STAGE(C, 0, s2));            \
  } while (0)

#define GEMM_PREAMBLE(Aptr, Bptr)                                                  \
  __shared__ __align__(16) short lds[49152]; /* 96 KiB */                          \
  int tid = threadIdx.x;                                                           \
  int lane = tid & 63, wid = tid >> 6;                                             \
  int l15 = lane & 15, l4 = lane >> 4;                                             \
  int wr = wid >> 1, wc = wid & 1;                                                 \
  int wr4 = wr * 4, wc4 = wc * 4;                                                  \
  int wprime = (lane * 16) ^ (lane & 32);                                          \
  int r_ = wprime >> 6;                                                            \
  int cs_ = (wprime & 63) >> 1;                                                    \
  const short* Asrc0 = (Aptr) + (size_t)(rowBase + wid * 16 + r_) * 2048 + cs_;    \
  const short* Asrc1 = (Aptr) + (size_t)(rowBase + (wid + 8) * 16 + r_) * 2048 + cs_; \
  const short* Bsrc0 = (Bptr) + (size_t)(colBase + wid * 16 + r_) * 2048 + cs_;    \
  int rdoff = l15 * 32 + ((l4 * 8) ^ ((l15 & 8) << 1));                            \
  f32x4 zero = {0.f, 0.f, 0.f, 0.f};                                               \
  f32x4 acc[4][4];                                                                 \
  _Pragma("unroll") for (int i = 0; i < 4; i++) _Pragma("unroll") for (int j = 0;  \
                                                                       j < 4; j++) \
      acc[i][j] = zero;                                                            \
  bf16x8 af[4], bfr[4];                                                            \
  STAGE(0, 0, 0);                                                                  \
  STAGE(0, 1, 0);                                                                  \
  STAGE(1, 0, 1);                                                                  \
  asm volatile("s_waitcnt vmcnt(6)" ::: "memory");                                 \
  __builtin_amdgcn_sched_barrier(0);                                               \
  asm volatile("s_barrier" ::: "memory");                                          \
  __builtin_amdgcn_sched_barrier(0);                                               \
  for (int it = 0; it < 16; ++it) {                                                \
    int m0 = it * 2;                                                               \
    KTILE(0, 1, m0);                                                               \
    KTILE(1, 0, m0 + 1);                                                           \
  }                                                                                \
  asm volatile("s_waitcnt vmcnt(0)" ::: "memory");                                 \
  __syncthreads();

// ---------------- QKV GEMM: grid 768 (= 3 exact rounds), R3 swizzle ----------------
__global__ __launch_bounds__(512, 2) void gemm_qkv_kernel(const short* __restrict__ A,
                                                          const short* __restrict__ Bt,
                                                          const float* __restrict__ bias,
                                                          short* __restrict__ q_bf,
                                                          short* __restrict__ k_bf,
                                                          short* __restrict__ vt,
                                                          float* __restrict__ cache) {
  int bid = blockIdx.x;  // R3 XCD-aware swizzle
  int s = (bid & 7) * 96 + (bid >> 3);
  int bx = s % 48, by = s / 48;
  int rowBase = by * 256, colBase = bx * 128;

  GEMM_PREAMBLE(A, Bt)

  // ---- epilogue ----
  int seg = colBase >> 11;      // 0=q 1=k 2=v (block-uniform: 16 blocks/segment)
  int colLoc = colBase & 2047;  // column within segment
  float scale = (seg == 0) ? 0.08838834764831845f : 1.0f;
  float bv[4];
#pragma unroll
  for (int nt = 0; nt < 4; nt++) bv[nt] = bias[colBase + wc * 64 + nt * 16 + l15];

  // stage C tile (256x128 bf16) through LDS
  short(*Cs)[136] = (short(*)[136])lds;  // 256 x 136 shorts = 68 KiB < 96 KiB
#pragma unroll
  for (int mt = 0; mt < 4; mt++)
#pragma unroll
    for (int nt = 0; nt < 4; nt++)
#pragma unroll
      for (int r = 0; r < 4; r++)
        Cs[wr * 64 + mt * 16 + l4 * 4 + r][wc * 64 + nt * 16 + l15] =
            f2bf((acc[mt][nt][r] + bv[nt]) * scale);
  __syncthreads();

  if (seg < 2) {  // q/k: linear 256B-contiguous stores
    short* outp = (seg == 0) ? q_bf : k_bf;
#pragma unroll
    for (int pp = 0; pp < 8; pp++) {
      int idx = pp * 512 + tid;
      int row = idx >> 4, c8 = (idx & 15) * 8;
      *(uint4*)(outp + (size_t)(rowBase + row) * 2048 + colLoc + c8) =
          *(const uint4*)&Cs[row][c8];
    }
  } else {  // v: permuted transpose to vt (fused vpost)
    int b_ = rowBase >> 11, rowLoc = rowBase & 2047;
    int hh = colLoc >> 7;  // this block's head
    short* vrow = vt + (size_t)((b_ * 16 + hh) * 128) * 2048;
    int tx = tid & 7, dbase = tid >> 3;  // dbase in 0..63
#pragma unroll
    for (int dd = 0; dd < 2; dd++) {
      int d = dbase + dd * 64;
#pragma unroll
      for (int g = 0; g < 4; g++) {
        short tmp[8];
#pragma unroll
        for (int j = 0; j < 8; j++) {
          int p = tx * 8 + j;
          int tl = (p & 32) + ((p & 1) << 4) + ((p >> 1) & 15);
          tmp[j] = Cs[g * 64 + tl][d];
        }
        *(uint4*)(vrow + (size_t)d * 2048 + rowLoc + g * 64 + tx * 8) = *(uint4*)tmp;
      }
    }
  }

  if (seg) {  // fp32 cache: k -> +0, v -> +2048 ; row index == b*2048+t
    int coff = (seg == 1) ? 0 : 2048;
#pragma unroll
    for (int mt = 0; mt < 4; mt++)
#pragma unroll
      for (int nt = 0; nt < 4; nt++) {
        int cc = coff + colLoc + wc * 64 + nt * 16 + l15;
#pragma unroll
        for (int r = 0; r < 4; r++) {
          int row = rowBase + wr * 64 + mt * 16 + l4 * 4 + r;
          cache[(size_t)row * 4096 + cc] = acc[mt][nt][r] + bv[nt];
        }
      }
  }
}

// ---------------- proj GEMM: same core, grid 256, R3 swizzle ----------------
__global__ __launch_bounds__(512, 2) void gemm_proj_kernel(const short* __restrict__ A,
                                                           const short* __restrict__ Bt,
                                                           const float* __restrict__ bias,
                                                           float* __restrict__ out_y) {
  int bid = blockIdx.x;  // R3 mapping
  int s = (bid & 7) * 32 + (bid >> 3);
  int bx = s % 16, by = s / 16;
  int rowBase = by * 256, colBase = bx * 128;

  GEMM_PREAMBLE(A, Bt)

#pragma unroll
  for (int mt = 0; mt < 4; mt++)
#pragma unroll
    for (int nt = 0; nt < 4; nt++) {
      int col = colBase + wc * 64 + nt * 16 + l15;
      float bvv = bias[col];
#pragma unroll
      for (int r = 0; r < 4; r++) {
        int row = rowBase + wr * 64 + mt * 16 + l4 * 4 + r;
        out_y[(size_t)row * 2048 + col] = acc[mt][nt][r] + bvv;  // 64B runs
      }
    }
}

// ---------------- fused causal flash attention (R7 proven + T5 setprio) ----------------
// Structure unchanged from the 396.7us run. NEW: s_setprio(1) around the QK and PV
// MFMA clusters (T5). Mechanism: 8 waves/CU at divergent phases (masked waves skip
// compute, staging waves issue memory) — the role-split regime where m191 measured
// +4-7% on attn; GEMM-style lockstep (m190) was null, but attn is not lockstep.
#define LDK 136  // K rows: 128 + 8 pad shorts
#define LDV 72   // V rows: 64 + 8 pad
#define LDP 72   // P rows: 64 + 8 pad

__global__ __launch_bounds__(512, 2) void attn_kernel(const short* __restrict__ qb,
                                                      const short* __restrict__ kb,
                                                      const short* __restrict__ vtb,
                                                      short* __restrict__ attout) {
  __shared__ short Ks[64 * LDK];      // 64 k x 128 d
  __shared__ short Vs[128 * LDV];     // 128 d x 64 k (t-permuted)
  __shared__ short Ps[8][32 * LDP];   // per wave: 32 q-rows x 64 k (t-permuted)

  int tid = threadIdx.x;
  int lane = tid & 63, wid = tid >> 6;
  int l15 = lane & 15, l4 = lane >> 4;
  int qlo = blockIdx.x, qhi = 15 - qlo;  // 128-row tile indices
  int h = blockIdx.y, b = blockIdx.z;
  int myqt = (wid < 4) ? qhi : qlo;
  int qrow0 = myqt * 128 + (wid & 3) * 32;  // this wave's 32 rows
  int kdiag = qrow0 >> 6;                   // the single diagonal k-tile for this wave
  int ktmax = 2 * qhi + 1;                  // block staging loop bound
  size_t qkbase = (size_t)b * 2048 * 2048 + (size_t)h * 128;
  size_t vbase = (size_t)((b * 16 + h) * 128) * 2048;

  bf16x8 qf[2][4];
#pragma unroll
  for (int m = 0; m < 2; m++)
#pragma unroll
    for (int kk = 0; kk < 4; kk++)
      qf[m][kk] =
          *(const bf16x8*)(qb + qkbase + (size_t)(qrow0 + m * 16 + l15) * 2048 + kk * 32 + l4 * 8);

  short onev = (short)0x3F80;  // bf16 1.0
  bf16x8 ones = {onev, onev, onev, onev, onev, onev, onev, onev};

  f32x4 zero = {0.f, 0.f, 0.f, 0.f};
  f32x4 o[2][8], ol[2];
#pragma unroll
  for (int m = 0; m < 2; m++) {
#pragma unroll
    for (int n = 0; n < 8; n++) o[m][n] = zero;
    ol[m] = zero;
  }

  // staging geometry (512 threads cover K 64x128 and V 128x64, 2 uint4 each)
  int c0 = tid, c1 = 512 + tid;
  int kr0 = c0 >> 4, kc0 = (c0 & 15) * 8;
  int kr1 = c1 >> 4, kc1 = (c1 & 15) * 8;
  int dr0 = c0 >> 3, tc0 = (c0 & 7) * 8;
  int dr1 = c1 >> 3, tc1 = (c1 & 7) * 8;
  const short* kA = kb + qkbase + (size_t)kr0 * 2048 + kc0;
  const short* kB = kb + qkbase + (size_t)kr1 * 2048 + kc1;
  const short* vA = vtb + vbase + (size_t)dr0 * 2048 + tc0;
  const short* vB = vtb + vbase + (size_t)dr1 * 2048 + tc1;

  // T14 prefetch: kt=0 tile -> regs
  uint4 krg0 = *(const uint4*)kA;
  uint4 krg1 = *(const uint4*)kB;
  uint4 vrg0 = *(const uint4*)vA;
  uint4 vrg1 = *(const uint4*)vB;

  for (int kt = 0; kt <= ktmax; kt++) {
    __syncthreads();  // previous tile's LDS reads complete
    *(uint4*)&Ks[kr0 * LDK + kc0] = krg0;
    *(uint4*)&Ks[kr1 * LDK + kc1] = krg1;
    *(uint4*)&Vs[dr0 * LDV + tc0] = vrg0;
    *(uint4*)&Vs[dr1 * LDV + tc1] = vrg1;
    if (kt < ktmax) {  // issue next-tile loads; latency hides under compute
      size_t ko = (size_t)(kt + 1) * 64 * 2048;
      int vo = (kt + 1) * 64;
      krg0 = *(const uint4*)(kA + ko);
      krg1 = *(const uint4*)(kB + ko);
      vrg0 = *(const uint4*)(vA + vo);
      vrg1 = *(const uint4*)(vB + vo);
    }
    __syncthreads();

    if (kt <= kdiag) {
      f32x4 s[2][4];
#pragma unroll
      for (int m = 0; m < 2; m++)
#pragma unroll
        for (int nt = 0; nt < 4; nt++) s[m][nt] = zero;
      __builtin_amdgcn_s_setprio(1);  // T5: QK cluster
#pragma unroll
      for (int kk = 0; kk < 4; kk++) {
#pragma unroll
        for (int nt = 0; nt < 4; nt++) {
          bf16x8 kf = *(const bf16x8*)&Ks[(nt * 16 + l15) * LDK + kk * 32 + l4 * 8];
          s[0][nt] = MFMA16(qf[0][kk], kf, s[0][nt]);
          s[1][nt] = MFMA16(qf[1][kk], kf, s[1][nt]);
        }
      }
      __builtin_amdgcn_s_setprio(0);

      if (kt == kdiag) {
        int kt0 = kt * 64;
#pragma unroll
        for (int m = 0; m < 2; m++)
#pragma unroll
          for (int nt = 0; nt < 4; nt++) {
            int colg = kt0 + nt * 16 + l15;
#pragma unroll
            for (int r = 0; r < 4; r++) {
              int rowg = qrow0 + m * 16 + l4 * 4 + r;
              if (colg > rowg) s[m][nt][r] = -1e30f;
            }
          }
      }

#pragma unroll
      for (int m = 0; m < 2; m++)
#pragma unroll
        for (int r = 0; r < 4; r++) {
          float p0 = __expf(s[m][0][r]);
          float p1 = __expf(s[m][1][r]);
          float p2 = __expf(s[m][2][r]);
          float p3 = __expf(s[m][3][r]);
          int prow = (m * 16 + l4 * 4 + r) * LDP;
          *(unsigned*)&Ps[wid][prow + 2 * l15] = pack2(p0, p1);
          *(unsigned*)&Ps[wid][prow + 32 + 2 * l15] = pack2(p2, p3);
        }

      __builtin_amdgcn_s_setprio(1);  // T5: PV cluster
#pragma unroll
      for (int kk = 0; kk < 2; kk++) {
        bf16x8 pf0 = *(const bf16x8*)&Ps[wid][l15 * LDP + kk * 32 + l4 * 8];
        bf16x8 pf1 = *(const bf16x8*)&Ps[wid][(16 + l15) * LDP + kk * 32 + l4 * 8];
        ol[0] = MFMA16(pf0, ones, ol[0]);
        ol[1] = MFMA16(pf1, ones, ol[1]);
#pragma unroll
        for (int n = 0; n < 8; n++) {
          bf16x8 vf = *(const bf16x8*)&Vs[(n * 16 + l15) * LDV + kk * 32 + l4 * 8];
          o[0][n] = MFMA16(pf0, vf, o[0][n]);
          o[1][n] = MFMA16(pf1, vf, o[1][n]);
        }
      }
      __builtin_amdgcn_s_setprio(0);
    }
  }

#pragma unroll
  for (int m = 0; m < 2; m++) {
    float rl[4];
#pragma unroll
    for (int r = 0; r < 4; r++) rl[r] = 1.0f / ol[m][r];
#pragma unroll
    for (int n = 0; n < 8; n++)
#pragma unroll
      for (int r = 0; r < 4; r++)
        attout[qkbase + (size_t)(qrow0 + m * 16 + l4 * 4 + r) * 2048 + n * 16 + l15] =
            f2bf(o[m][n][r] * rl[r]);
  }
}

// ---------------- launch ----------------
extern "C" void kernel_launch(void* const* d_in, const int* in_sizes, int n_in, void* d_out,
                              int out_size, void* d_ws, size_t ws_size, hipStream_t stream) {
  const float* x = (const float*)d_in[0];
  const float* W_attn = (const float*)d_in[2];
  const float* b_attn = (const float*)d_in[3];
  const float* W_proj = (const float*)d_in[4];
  const float* b_proj = (const float*)d_in[5];
  float* y = (float*)d_out;
  float* cache = y + (size_t)4096 * 2048;

  char* p = (char*)d_ws;
  short* x_bf = (short*)p;   p += (size_t)8388608 * 2;
  short* q_bf = (short*)p;   p += (size_t)8388608 * 2;
  short* k_bf = (short*)p;   p += (size_t)8388608 * 2;
  short* vt_bf = (short*)p;  p += (size_t)8388608 * 2;
  short* att_bf = (short*)p; p += (size_t)8388608 * 2;
  short* wt_attn = (short*)p; p += (size_t)12582912 * 2;
  short* wt_proj = (short*)p; p += (size_t)4194304 * 2;

  prep_kernel<<<8192, 256, 0, stream>>>(x, x_bf, W_attn, wt_attn, W_proj, wt_proj);
  gemm_qkv_kernel<<<768, 512, 0, stream>>>(x_bf, wt_attn, b_attn, q_bf, k_bf, vt_bf, cache);
  attn_kernel<<<dim3(8, 16, 2), 512, 0, stream>>>(q_bf, k_bf, vt_bf, att_bf);
  gemm_proj_kernel<<<256, 512, 0, stream>>>(att_bf, wt_proj, b_proj, y);
}